// Round 7
// baseline (320.576 us; speedup 1.0000x reference)
//
#include <hip/hip_runtime.h>

#define Bn 128
#define Hn 28
#define Wn 28
#define Cn 512
#define Pn (Hn * Wn)       // 784 spatial positions
#define CCH 16             // channels per block
#define NCB (Cn / CCH)     // 32 c-chunks
#define NJ 12              // full j-iterations (p = pg + 64*j), 64*12 = 768
#define PTAIL (Pn - 64 * NJ)  // 16 tail positions, handled by pg < 16

// Native vector types for __builtin_nontemporal_{load,store}.
typedef float f4 __attribute__((ext_vector_type(4)));

__device__ __forceinline__ void nt_store4(float* p, float a, float b, float c, float d) {
    f4 v = {a, b, c, d};
    __builtin_nontemporal_store(v, reinterpret_cast<f4*>(p));
}
__device__ __forceinline__ f4 nt_load4(const float* p) {
    return __builtin_nontemporal_load(reinterpret_cast<const f4*>(p));
}

// ---------------------------------------------------------------------------
// Single fused kernel. Block = 256 threads owns (b, 16-channel stripe),
// all 784 spatial positions. Thread t: c4 = t&3 (4 consecutive channels),
// pg = t>>2 (p = pg + 64*j, 13 rows). x stripe lives in VGPRs (13 float4):
//   phase 1: load x once (NT: never re-read), per-lane argmax partials for
//            its 4 channels computed under the load shadow.
//   phase 2: 8 KB LDS fold of 64 partials per channel. Tie-aware compare
//            (val >, or == and smaller idx) gives exact np.argmax first-max
//            semantics independent of partial ordering.
//   phase 3: gather 4 template rows (L2-resident t_p), NT-store o0/o1/o2
//            straight from registers. Zero x re-read, zero HBM scratch.
// ---------------------------------------------------------------------------
__global__ void fused_mask(const float* __restrict__ x,
                           const float* __restrict__ tp,
                           float* __restrict__ o0,
                           float* __restrict__ o1,
                           float* __restrict__ o2) {
    __shared__ uint2 part_s[64][CCH];   // [pg][c] partials (8 KB)
    __shared__ int sidx[CCH];

    int t  = threadIdx.x;
    int c4 = t & 3;
    int pg = t >> 2;
    int cc = blockIdx.x & (NCB - 1);
    int b  = blockIdx.x >> 5;
    int c0 = cc * CCH + c4 * 4;         // first of this thread's 4 channels

    const float* xb = x + (size_t)b * (Pn * Cn) + c0;
    bool tail = (pg < PTAIL);

    // ---- phase 1: load x stripe into registers (13 independent loads) ----
    f4 xv[NJ + 1];
#pragma unroll
    for (int j = 0; j < NJ; ++j)
        xv[j] = nt_load4(xb + (size_t)(pg + 64 * j) * Cn);
    if (tail)
        xv[NJ] = nt_load4(xb + (size_t)(768 + pg) * Cn);

    // per-lane argmax partials (ascending p within thread, strict >)
    float bv0 = -INFINITY, bv1 = -INFINITY, bv2 = -INFINITY, bv3 = -INFINITY;
    int bi0 = 0, bi1 = 0, bi2 = 0, bi3 = 0;
#pragma unroll
    for (int j = 0; j < NJ; ++j) {
        int p = pg + 64 * j;
        if (xv[j].x > bv0) { bv0 = xv[j].x; bi0 = p; }
        if (xv[j].y > bv1) { bv1 = xv[j].y; bi1 = p; }
        if (xv[j].z > bv2) { bv2 = xv[j].z; bi2 = p; }
        if (xv[j].w > bv3) { bv3 = xv[j].w; bi3 = p; }
    }
    if (tail) {
        int p = 768 + pg;
        if (xv[NJ].x > bv0) { bv0 = xv[NJ].x; bi0 = p; }
        if (xv[NJ].y > bv1) { bv1 = xv[NJ].y; bi1 = p; }
        if (xv[NJ].z > bv2) { bv2 = xv[NJ].z; bi2 = p; }
        if (xv[NJ].w > bv3) { bv3 = xv[NJ].w; bi3 = p; }
    }
    part_s[pg][c4 * 4 + 0] = make_uint2(__float_as_uint(bv0), (unsigned)bi0);
    part_s[pg][c4 * 4 + 1] = make_uint2(__float_as_uint(bv1), (unsigned)bi1);
    part_s[pg][c4 * 4 + 2] = make_uint2(__float_as_uint(bv2), (unsigned)bi2);
    part_s[pg][c4 * 4 + 3] = make_uint2(__float_as_uint(bv3), (unsigned)bi3);
    __syncthreads();

    // ---- phase 2: fold 64 partials per channel (threads 0..15) ----
    if (t < CCH) {
        float best = -INFINITY;
        int bi = 0;
#pragma unroll 8
        for (int g = 0; g < 64; ++g) {
            uint2 r = part_s[g][t];
            float v = __uint_as_float(r.x);
            int i = (int)r.y;
            if (v > best || (v == best && i < bi)) { best = v; bi = i; }
        }
        sidx[t] = bi;
    }
    __syncthreads();

    // ---- phase 3: template gather + outputs from registers ----
    int4 iv = *reinterpret_cast<const int4*>(sidx + c4 * 4);
    const float* t0p = tp + (size_t)iv.x * Pn;
    const float* t1p = tp + (size_t)iv.y * Pn;
    const float* t2p = tp + (size_t)iv.z * Pn;
    const float* t3p = tp + (size_t)iv.w * Pn;

    size_t obase = (size_t)b * (Pn * Cn) + c0;
    int jn = tail ? NJ + 1 : NJ;
#pragma unroll
    for (int j = 0; j <= NJ; ++j) {
        if (j >= jn) break;
        int p = pg + 64 * j;
        float ta = t0p[p], tb = t1p[p], tc = t2p[p], td = t3p[p];
        size_t q = obase + (size_t)p * Cn;
        f4 v = xv[j];
        nt_store4(o1 + q, v.x, v.y, v.z, v.w);
        nt_store4(o0 + q, fmaxf(v.x * ta, 0.f), fmaxf(v.y * tb, 0.f),
                          fmaxf(v.z * tc, 0.f), fmaxf(v.w * td, 0.f));
        nt_store4(o2 + q, ta, tb, tc, td);
    }
}

extern "C" void kernel_launch(void* const* d_in, const int* in_sizes, int n_in,
                              void* d_out, int out_size, void* d_ws, size_t ws_size,
                              hipStream_t stream) {
    const float* x  = (const float*)d_in[0];   // [B,H,W,C] fp32
    const float* tp = (const float*)d_in[1];   // [H,W,H,W] fp32

    const size_t N = (size_t)Bn * Pn * Cn;
    float* o0 = (float*)d_out;                 // masked
    float* o1 = o0 + N;                        // x copy
    float* o2 = o0 + 2 * N;                    // templates

    fused_mask<<<Bn * NCB, 256, 0, stream>>>(x, tp, o0, o1, o2);
}

// Round 8
// 180.392 us; speedup vs baseline: 1.7771x; 1.7771x over previous
//
#include <hip/hip_runtime.h>

#define Bn 128
#define Hn 28
#define Wn 28
#define Cn 512
#define Pn (Hn * Wn)       // 784 spatial positions
#define CCH 32             // channels per block -> 128-B segments (1 L2 line)
#define NCB (Cn / CCH)     // 16 c-chunks
#define NPG 64             // p-groups per block (512 threads / 8 c-lanes)
#define NJ 12              // full j-iterations: p = pg + 64*j, 64*12 = 768
#define PTAIL (Pn - 64 * NJ)  // 16 tail positions (pg < 16 handle p = 768+pg)

// Native vector types for __builtin_nontemporal_{load,store}.
typedef float f4 __attribute__((ext_vector_type(4)));

__device__ __forceinline__ void nt_store4(float* p, float a, float b, float c, float d) {
    f4 v = {a, b, c, d};
    __builtin_nontemporal_store(v, reinterpret_cast<f4*>(p));
}
__device__ __forceinline__ f4 nt_load4(const float* p) {
    return __builtin_nontemporal_load(reinterpret_cast<const f4*>(p));
}

// ---------------------------------------------------------------------------
// Single fused kernel, R7 structure with fixed access granularity.
// Block = 512 threads owns (b, 32-channel stripe) x all 784 p.
// Thread: cl = t&7 (4 consecutive channels, 16B), pg = t>>3 (p = pg+64j).
// Wave memory op = 8 p-rows x one aligned 128-B segment -> no partial-line
// traffic (R7's 64-B segments caused 2x read+write amplification).
//   phase 1: NT-load x stripe into 13 VGPR float4, per-lane argmax partials.
//   phase 2: 16 KB LDS fold, tie-aware compare == np.argmax first-max.
//   phase 3: tp gather (L2-resident) + NT-store o0/o1/o2 from registers.
// ---------------------------------------------------------------------------
__global__ __launch_bounds__(512) void fused_mask(const float* __restrict__ x,
                                                  const float* __restrict__ tp,
                                                  float* __restrict__ o0,
                                                  float* __restrict__ o1,
                                                  float* __restrict__ o2) {
    __shared__ uint2 part_s[NPG][CCH];   // [pg][c] partials (16 KB)
    __shared__ int sidx[CCH];

    int t  = threadIdx.x;
    int cl = t & 7;
    int pg = t >> 3;
    int cc = blockIdx.x & (NCB - 1);
    int b  = blockIdx.x >> 4;
    int c0 = cc * CCH + cl * 4;          // first of this thread's 4 channels

    const float* xb = x + (size_t)b * (Pn * Cn) + c0;
    bool tail = (pg < PTAIL);

    // ---- phase 1: load x stripe into registers (12-13 independent loads) ----
    f4 xv[NJ + 1];
#pragma unroll
    for (int j = 0; j < NJ; ++j)
        xv[j] = nt_load4(xb + (size_t)(pg + 64 * j) * Cn);
    if (tail)
        xv[NJ] = nt_load4(xb + (size_t)(768 + pg) * Cn);

    // per-lane argmax partials (ascending p within thread, strict >)
    float bv0 = -INFINITY, bv1 = -INFINITY, bv2 = -INFINITY, bv3 = -INFINITY;
    int bi0 = 0, bi1 = 0, bi2 = 0, bi3 = 0;
#pragma unroll
    for (int j = 0; j < NJ; ++j) {
        int p = pg + 64 * j;
        if (xv[j].x > bv0) { bv0 = xv[j].x; bi0 = p; }
        if (xv[j].y > bv1) { bv1 = xv[j].y; bi1 = p; }
        if (xv[j].z > bv2) { bv2 = xv[j].z; bi2 = p; }
        if (xv[j].w > bv3) { bv3 = xv[j].w; bi3 = p; }
    }
    if (tail) {
        int p = 768 + pg;
        if (xv[NJ].x > bv0) { bv0 = xv[NJ].x; bi0 = p; }
        if (xv[NJ].y > bv1) { bv1 = xv[NJ].y; bi1 = p; }
        if (xv[NJ].z > bv2) { bv2 = xv[NJ].z; bi2 = p; }
        if (xv[NJ].w > bv3) { bv3 = xv[NJ].w; bi3 = p; }
    }
    part_s[pg][cl * 4 + 0] = make_uint2(__float_as_uint(bv0), (unsigned)bi0);
    part_s[pg][cl * 4 + 1] = make_uint2(__float_as_uint(bv1), (unsigned)bi1);
    part_s[pg][cl * 4 + 2] = make_uint2(__float_as_uint(bv2), (unsigned)bi2);
    part_s[pg][cl * 4 + 3] = make_uint2(__float_as_uint(bv3), (unsigned)bi3);
    __syncthreads();

    // ---- phase 2: fold 64 partials per channel (threads 0..31) ----
    // Tie-aware: smaller p wins on equal value -> exact np first-max semantics.
    if (t < CCH) {
        float best = -INFINITY;
        int bi = 0;
#pragma unroll 8
        for (int g = 0; g < NPG; ++g) {
            uint2 r = part_s[g][t];
            float v = __uint_as_float(r.x);
            int i = (int)r.y;
            if (v > best || (v == best && i < bi)) { best = v; bi = i; }
        }
        sidx[t] = bi;
    }
    __syncthreads();

    // ---- phase 3: template gather + outputs from registers ----
    int4 iv = *reinterpret_cast<const int4*>(sidx + cl * 4);
    const float* t0p = tp + (size_t)iv.x * Pn;
    const float* t1p = tp + (size_t)iv.y * Pn;
    const float* t2p = tp + (size_t)iv.z * Pn;
    const float* t3p = tp + (size_t)iv.w * Pn;

    size_t obase = (size_t)b * (Pn * Cn) + c0;
#pragma unroll
    for (int j = 0; j < NJ; ++j) {
        int p = pg + 64 * j;
        float ta = t0p[p], tb = t1p[p], tc = t2p[p], td = t3p[p];
        size_t q = obase + (size_t)p * Cn;
        f4 v = xv[j];
        nt_store4(o1 + q, v.x, v.y, v.z, v.w);
        nt_store4(o0 + q, fmaxf(v.x * ta, 0.f), fmaxf(v.y * tb, 0.f),
                          fmaxf(v.z * tc, 0.f), fmaxf(v.w * td, 0.f));
        nt_store4(o2 + q, ta, tb, tc, td);
    }
    if (tail) {
        int p = 768 + pg;
        float ta = t0p[p], tb = t1p[p], tc = t2p[p], td = t3p[p];
        size_t q = obase + (size_t)p * Cn;
        f4 v = xv[NJ];
        nt_store4(o1 + q, v.x, v.y, v.z, v.w);
        nt_store4(o0 + q, fmaxf(v.x * ta, 0.f), fmaxf(v.y * tb, 0.f),
                          fmaxf(v.z * tc, 0.f), fmaxf(v.w * td, 0.f));
        nt_store4(o2 + q, ta, tb, tc, td);
    }
}

extern "C" void kernel_launch(void* const* d_in, const int* in_sizes, int n_in,
                              void* d_out, int out_size, void* d_ws, size_t ws_size,
                              hipStream_t stream) {
    const float* x  = (const float*)d_in[0];   // [B,H,W,C] fp32
    const float* tp = (const float*)d_in[1];   // [H,W,H,W] fp32

    const size_t N = (size_t)Bn * Pn * Cn;
    float* o0 = (float*)d_out;                 // masked
    float* o1 = o0 + N;                        // x copy
    float* o2 = o0 + 2 * N;                    // templates

    fused_mask<<<Bn * NCB, 512, 0, stream>>>(x, tp, o0, o1, o2);
}

// Round 9
// 179.914 us; speedup vs baseline: 1.7818x; 1.0027x over previous
//
#include <hip/hip_runtime.h>

#define Bn 128
#define Hn 28
#define Wn 28
#define Cn 512
#define Pn (Hn * Wn)       // 784 spatial positions
#define CCH 32             // channels per block -> 128-B segments (1 L2 line)
#define NCB (Cn / CCH)     // 16 c-chunks
#define NQ (Pn / 4)        // 196 p-quads (p = qi*4 + q)
#define NJF 3              // full j iterations: qi = pg + 64*j -> 192 quads
#define QTAIL (NQ - 64 * NJF)  // 4 tail quads, handled by pg < 4

// Native vector types for __builtin_nontemporal_{load,store} and for
// subscriptable 16-B template loads.
typedef float f4 __attribute__((ext_vector_type(4)));

__device__ __forceinline__ void nt_store4(float* p, float a, float b, float c, float d) {
    f4 v = {a, b, c, d};
    __builtin_nontemporal_store(v, reinterpret_cast<f4*>(p));
}
__device__ __forceinline__ f4 nt_load4(const float* p) {
    return __builtin_nontemporal_load(reinterpret_cast<const f4*>(p));
}

// ---------------------------------------------------------------------------
// Single fused kernel, R8 structure with p-QUAD thread mapping so the
// template gather is vector (R8's stride-64 p mapping made tp loads 4-B
// divergent scalar gathers -- ~850K serialized VMEM instrs).
// Block = 512 threads owns (b, 32-channel stripe) x all 784 p.
// Thread: cl = t&7 (4 consecutive channels), pg = t>>3 (p-quads pg+64j).
//   phase 1: NT-load x stripe (16 f4 in VGPRs), per-lane argmax partials.
//   phase 2: 16 KB LDS fold, tie-aware compare == np.argmax first-max.
//   phase 3: tp rows as aligned f4 (row len 3136 B = 196*16 -> qi*16 offset
//            is 16-B aligned; per wave 8 rows x 128 B contiguous), NT-store
//            o0/o1/o2 from registers. All streams 128-B segments.
// ---------------------------------------------------------------------------
__global__ __launch_bounds__(512) void fused_mask(const float* __restrict__ x,
                                                  const float* __restrict__ tp,
                                                  float* __restrict__ o0,
                                                  float* __restrict__ o1,
                                                  float* __restrict__ o2) {
    __shared__ uint2 part_s[64][CCH];   // [pg][c] partials (16 KB)
    __shared__ int sidx[CCH];

    int t  = threadIdx.x;
    int cl = t & 7;
    int pg = t >> 3;
    int cc = blockIdx.x & (NCB - 1);
    int b  = blockIdx.x >> 4;
    int c0 = cc * CCH + cl * 4;          // first of this thread's 4 channels

    const float* xb = x + (size_t)b * (Pn * Cn) + c0;
    bool tail = (pg < QTAIL);

    // ---- phase 1: load x stripe into registers ----
    f4 xv[NJF + 1][4];
#pragma unroll
    for (int j = 0; j < NJF; ++j) {
        int p0 = (pg + 64 * j) * 4;
#pragma unroll
        for (int q = 0; q < 4; ++q)
            xv[j][q] = nt_load4(xb + (size_t)(p0 + q) * Cn);
    }
    if (tail) {
        int p0 = (64 * NJF + pg) * 4;
#pragma unroll
        for (int q = 0; q < 4; ++q)
            xv[NJF][q] = nt_load4(xb + (size_t)(p0 + q) * Cn), (void)0;
    }
    if (tail) {
        int p0 = (64 * NJF + pg) * 4;
#pragma unroll
        for (int q = 0; q < 4; ++q)
            xv[NJF][q] = nt_load4(xb + (size_t)(p0 + q) * Cn);
    }

    // per-lane argmax partials (ascending p within thread, strict >)
    float bv0 = -INFINITY, bv1 = -INFINITY, bv2 = -INFINITY, bv3 = -INFINITY;
    int bi0 = 0, bi1 = 0, bi2 = 0, bi3 = 0;
#pragma unroll
    for (int j = 0; j < NJF; ++j) {
        int p0 = (pg + 64 * j) * 4;
#pragma unroll
        for (int q = 0; q < 4; ++q) {
            int p = p0 + q;
            if (xv[j][q].x > bv0) { bv0 = xv[j][q].x; bi0 = p; }
            if (xv[j][q].y > bv1) { bv1 = xv[j][q].y; bi1 = p; }
            if (xv[j][q].z > bv2) { bv2 = xv[j][q].z; bi2 = p; }
            if (xv[j][q].w > bv3) { bv3 = xv[j][q].w; bi3 = p; }
        }
    }
    if (tail) {
        int p0 = (64 * NJF + pg) * 4;
#pragma unroll
        for (int q = 0; q < 4; ++q) {
            int p = p0 + q;
            if (xv[NJF][q].x > bv0) { bv0 = xv[NJF][q].x; bi0 = p; }
            if (xv[NJF][q].y > bv1) { bv1 = xv[NJF][q].y; bi1 = p; }
            if (xv[NJF][q].z > bv2) { bv2 = xv[NJF][q].z; bi2 = p; }
            if (xv[NJF][q].w > bv3) { bv3 = xv[NJF][q].w; bi3 = p; }
        }
    }
    part_s[pg][cl * 4 + 0] = make_uint2(__float_as_uint(bv0), (unsigned)bi0);
    part_s[pg][cl * 4 + 1] = make_uint2(__float_as_uint(bv1), (unsigned)bi1);
    part_s[pg][cl * 4 + 2] = make_uint2(__float_as_uint(bv2), (unsigned)bi2);
    part_s[pg][cl * 4 + 3] = make_uint2(__float_as_uint(bv3), (unsigned)bi3);
    __syncthreads();

    // ---- phase 2: fold 64 partials per channel (threads 0..31) ----
    // Tie-aware: smaller p wins on equal value -> exact np first-max semantics.
    if (t < CCH) {
        float best = -INFINITY;
        int bi = 0;
#pragma unroll 8
        for (int g = 0; g < 64; ++g) {
            uint2 r = part_s[g][t];
            float v = __uint_as_float(r.x);
            int i = (int)r.y;
            if (v > best || (v == best && i < bi)) { best = v; bi = i; }
        }
        sidx[t] = bi;
    }
    __syncthreads();

    // ---- phase 3: vector template gather + outputs from registers ----
    int4 iv = *reinterpret_cast<const int4*>(sidx + cl * 4);
    const float* t0p = tp + (size_t)iv.x * Pn;
    const float* t1p = tp + (size_t)iv.y * Pn;
    const float* t2p = tp + (size_t)iv.z * Pn;
    const float* t3p = tp + (size_t)iv.w * Pn;

    size_t obase = (size_t)b * (Pn * Cn) + c0;
#pragma unroll
    for (int j = 0; j <= NJF; ++j) {
        if (j == NJF && !tail) break;
        int p0 = (j == NJF) ? (64 * NJF + pg) * 4 : (pg + 64 * j) * 4;
        f4 ta = *reinterpret_cast<const f4*>(t0p + p0);
        f4 tb = *reinterpret_cast<const f4*>(t1p + p0);
        f4 tc = *reinterpret_cast<const f4*>(t2p + p0);
        f4 td = *reinterpret_cast<const f4*>(t3p + p0);
#pragma unroll
        for (int q = 0; q < 4; ++q) {
            size_t qoff = obase + (size_t)(p0 + q) * Cn;
            f4 v = xv[j][q];
            nt_store4(o1 + qoff, v.x, v.y, v.z, v.w);
            nt_store4(o0 + qoff, fmaxf(v.x * ta[q], 0.f), fmaxf(v.y * tb[q], 0.f),
                                 fmaxf(v.z * tc[q], 0.f), fmaxf(v.w * td[q], 0.f));
            nt_store4(o2 + qoff, ta[q], tb[q], tc[q], td[q]);
        }
    }
}

extern "C" void kernel_launch(void* const* d_in, const int* in_sizes, int n_in,
                              void* d_out, int out_size, void* d_ws, size_t ws_size,
                              hipStream_t stream) {
    const float* x  = (const float*)d_in[0];   // [B,H,W,C] fp32
    const float* tp = (const float*)d_in[1];   // [H,W,H,W] fp32

    const size_t N = (size_t)Bn * Pn * Cn;
    float* o0 = (float*)d_out;                 // masked
    float* o1 = o0 + N;                        // x copy
    float* o2 = o0 + 2 * N;                    // templates

    fused_mask<<<Bn * NCB, 512, 0, stream>>>(x, tp, o0, o1, o2);
}

// Round 10
// 165.881 us; speedup vs baseline: 1.9326x; 1.0846x over previous
//
#include <hip/hip_runtime.h>

#define Bn 128
#define Hn 28
#define Wn 28
#define Cn 512
#define Pn (Hn * Wn)      // 784 spatial positions
#define SCH 8             // spatial chunks for argmax parallelism
#define PCH (Pn / SCH)    // 98 positions per chunk
#define PPB 56            // p per block in mask kernel (784 = 14*56)
#define PPT 28            // p per thread (half-block)

// Native vector types for __builtin_nontemporal_{load,store}.
typedef float f4 __attribute__((ext_vector_type(4)));

__device__ __forceinline__ void nt_store4(float* p, float a, float b, float c, float d) {
    f4 v = {a, b, c, d};
    __builtin_nontemporal_store(v, reinterpret_cast<f4*>(p));
}
__device__ __forceinline__ f4 nt_load4(const float* p) {
    return __builtin_nontemporal_load(reinterpret_cast<const f4*>(p));
}

// ---------------------------------------------------------------------------
// Kernel 1: PURE-READ argmax partials. Writes only 4.2 MB of partials, so x
// (205 MB) is left nearly intact in the 256 MB L3 for kernel 2's re-read.
// (R5 wrote o1 here, churning 410 MB through L3 and evicting x -- that was
// the re-read's HBM cost.) Thread owns 4 consecutive c over one 98-p chunk;
// wave ops are 1 KB contiguous; blocks stream full 2 KB rows sequentially.
// ---------------------------------------------------------------------------
__global__ void argmax_partial(const float* __restrict__ x,
                               uint2* __restrict__ part) {
    int s = blockIdx.x & (SCH - 1);
    int b = blockIdx.x >> 3;
    int c0 = threadIdx.x * 4;

    const float* xp = x + (size_t)b * Pn * Cn + c0;
    int p0 = s * PCH;

    float b0 = -INFINITY, b1 = -INFINITY, b2 = -INFINITY, b3 = -INFINITY;
    int i0 = p0, i1 = p0, i2 = p0, i3 = p0;
#pragma unroll 7
    for (int i = 0; i < PCH; ++i) {
        float4 v = *reinterpret_cast<const float4*>(xp + (size_t)(p0 + i) * Cn);
        if (v.x > b0) { b0 = v.x; i0 = p0 + i; }
        if (v.y > b1) { b1 = v.y; i1 = p0 + i; }
        if (v.z > b2) { b2 = v.z; i2 = p0 + i; }
        if (v.w > b3) { b3 = v.w; i3 = p0 + i; }
    }
    // [s][b][c] layout; 32 B/thread contiguous, written as two dwordx4.
    uint4* o = reinterpret_cast<uint4*>(part + ((size_t)s * Bn + b) * Cn + c0);
    o[0] = make_uint4(__float_as_uint(b0), (unsigned)i0,
                      __float_as_uint(b1), (unsigned)i1);
    o[1] = make_uint4(__float_as_uint(b2), (unsigned)i2,
                      __float_as_uint(b3), (unsigned)i3);
}

// ---------------------------------------------------------------------------
// Kernel 2: inline partial-fold + ALL output writes.
//   threads 0..127 fold the 8 chunk partials (ascending s = ascending p,
//   strict > -> exact np.argmax first-max) for 4 channels each into LDS;
//   then all 256 threads: re-read x (NT load, should be L3-resident from k1),
//   gather 4 template rows per-lane-sequential (t_p L2-resident), and
//   NT-store o0 = relu(x*t), o1 = x, o2 = t (streaming writes: don't evict x).
// Wave ops 1 KB contiguous; blocks stream full rows sequentially.
// ---------------------------------------------------------------------------
__global__ void mask_outputs(const float* __restrict__ x,
                             const float* __restrict__ tp,
                             const uint2* __restrict__ part,
                             float* __restrict__ o0,
                             float* __restrict__ o1,
                             float* __restrict__ o2) {
    __shared__ int sidx[Cn];

    int pc = blockIdx.x % 14;
    int b  = blockIdx.x / 14;
    int t  = threadIdx.x;

    if (t < 128) {
        int c0 = t * 4;
        const uint2* pp = part + (size_t)b * Cn + c0;
        float v0 = -INFINITY, v1 = -INFINITY, v2 = -INFINITY, v3 = -INFINITY;
        int j0 = 0, j1 = 0, j2 = 0, j3 = 0;
#pragma unroll
        for (int s = 0; s < SCH; ++s) {
            const uint2* q = pp + (size_t)s * (Bn * Cn);
            uint4 a = *reinterpret_cast<const uint4*>(q);      // (v0,i0,v1,i1)
            uint4 c = *reinterpret_cast<const uint4*>(q + 2);  // (v2,i2,v3,i3)
            float f0 = __uint_as_float(a.x), f1 = __uint_as_float(a.z);
            float f2 = __uint_as_float(c.x), f3 = __uint_as_float(c.z);
            if (f0 > v0) { v0 = f0; j0 = (int)a.y; }
            if (f1 > v1) { v1 = f1; j1 = (int)a.w; }
            if (f2 > v2) { v2 = f2; j2 = (int)c.y; }
            if (f3 > v3) { v3 = f3; j3 = (int)c.w; }
        }
        sidx[c0 + 0] = j0;
        sidx[c0 + 1] = j1;
        sidx[c0 + 2] = j2;
        sidx[c0 + 3] = j3;
    }
    __syncthreads();

    int ci = t & 127;
    int c0 = ci * 4;
    int ph = t >> 7;
    int p0 = pc * PPB + ph * PPT;

    int4 iv = *reinterpret_cast<const int4*>(sidx + c0);
    const float* t0p = tp + (size_t)iv.x * Pn;
    const float* t1p = tp + (size_t)iv.y * Pn;
    const float* t2p = tp + (size_t)iv.z * Pn;
    const float* t3p = tp + (size_t)iv.w * Pn;

    size_t xbase = (size_t)b * Pn * Cn + c0;

#pragma unroll
    for (int j = 0; j < PPT; j += 4) {
        int p = p0 + j;
        // 4 template rows, 4 consecutive p each (per-lane sequential, L2-hot)
        float4 ta = *reinterpret_cast<const float4*>(t0p + p);
        float4 tb = *reinterpret_cast<const float4*>(t1p + p);
        float4 tc = *reinterpret_cast<const float4*>(t2p + p);
        float4 td = *reinterpret_cast<const float4*>(t3p + p);
        // x re-read: L3-resident from kernel 1; NT = last use, evict-first.
        f4 x0 = nt_load4(x + xbase + (size_t)(p + 0) * Cn);
        f4 x1 = nt_load4(x + xbase + (size_t)(p + 1) * Cn);
        f4 x2 = nt_load4(x + xbase + (size_t)(p + 2) * Cn);
        f4 x3 = nt_load4(x + xbase + (size_t)(p + 3) * Cn);

        size_t q0 = xbase + (size_t)(p + 0) * Cn;
        size_t q1 = xbase + (size_t)(p + 1) * Cn;
        size_t q2 = xbase + (size_t)(p + 2) * Cn;
        size_t q3 = xbase + (size_t)(p + 3) * Cn;

        // o1 = x copy
        nt_store4(o1 + q0, x0.x, x0.y, x0.z, x0.w);
        nt_store4(o1 + q1, x1.x, x1.y, x1.z, x1.w);
        nt_store4(o1 + q2, x2.x, x2.y, x2.z, x2.w);
        nt_store4(o1 + q3, x3.x, x3.y, x3.z, x3.w);
        // o0 = relu(x * t)
        nt_store4(o0 + q0, fmaxf(x0.x * ta.x, 0.f), fmaxf(x0.y * tb.x, 0.f),
                           fmaxf(x0.z * tc.x, 0.f), fmaxf(x0.w * td.x, 0.f));
        nt_store4(o0 + q1, fmaxf(x1.x * ta.y, 0.f), fmaxf(x1.y * tb.y, 0.f),
                           fmaxf(x1.z * tc.y, 0.f), fmaxf(x1.w * td.y, 0.f));
        nt_store4(o0 + q2, fmaxf(x2.x * ta.z, 0.f), fmaxf(x2.y * tb.z, 0.f),
                           fmaxf(x2.z * tc.z, 0.f), fmaxf(x2.w * td.z, 0.f));
        nt_store4(o0 + q3, fmaxf(x3.x * ta.w, 0.f), fmaxf(x3.y * tb.w, 0.f),
                           fmaxf(x3.z * tc.w, 0.f), fmaxf(x3.w * td.w, 0.f));
        // o2 = templates
        nt_store4(o2 + q0, ta.x, tb.x, tc.x, td.x);
        nt_store4(o2 + q1, ta.y, tb.y, tc.y, td.y);
        nt_store4(o2 + q2, ta.z, tb.z, tc.z, td.z);
        nt_store4(o2 + q3, ta.w, tb.w, tc.w, td.w);
    }
}

extern "C" void kernel_launch(void* const* d_in, const int* in_sizes, int n_in,
                              void* d_out, int out_size, void* d_ws, size_t ws_size,
                              hipStream_t stream) {
    const float* x  = (const float*)d_in[0];   // [B,H,W,C] fp32
    const float* tp = (const float*)d_in[1];   // [H,W,H,W] fp32

    const size_t N = (size_t)Bn * Pn * Cn;
    float* o0 = (float*)d_out;                 // masked
    float* o1 = o0 + N;                        // x copy
    float* o2 = o0 + 2 * N;                    // templates

    // Workspace: partials [SCH][Bn][Cn] uint2 = 4.19 MB (same as R2's proven fit).
    uint2* part = (uint2*)d_ws;

    argmax_partial<<<Bn * SCH, 128, 0, stream>>>(x, part);
    mask_outputs<<<Bn * 14, 256, 0, stream>>>(x, tp, part, o0, o1, o2);
}

// Round 11
// 163.662 us; speedup vs baseline: 1.9588x; 1.0136x over previous
//
#include <hip/hip_runtime.h>

#define Bn 128
#define Hn 28
#define Wn 28
#define Cn 512
#define Pn (Hn * Wn)      // 784 spatial positions
#define SCH 8             // spatial chunks for argmax parallelism
#define PCH (Pn / SCH)    // 98 positions per chunk
#define PPB 56            // p per block in mask kernel (784 = 14*56)
#define PPT 28            // p per thread (half-block)

// Native vector type for __builtin_nontemporal_store.
typedef float f4 __attribute__((ext_vector_type(4)));

__device__ __forceinline__ void nt_store4(float* p, float a, float b, float c, float d) {
    f4 v = {a, b, c, d};
    __builtin_nontemporal_store(v, reinterpret_cast<f4*>(p));
}

// ---------------------------------------------------------------------------
// Kernel 1: PURE-READ argmax partials, REGULAR loads (allocate x in the
// 256 MB memory-side LLC; k1 writes only 4.2 MB so x stays resident).
// ---------------------------------------------------------------------------
__global__ void argmax_partial(const float* __restrict__ x,
                               uint2* __restrict__ part) {
    int s = blockIdx.x & (SCH - 1);
    int b = blockIdx.x >> 3;
    int c0 = threadIdx.x * 4;

    const float* xp = x + (size_t)b * Pn * Cn + c0;
    int p0 = s * PCH;

    float b0 = -INFINITY, b1 = -INFINITY, b2 = -INFINITY, b3 = -INFINITY;
    int i0 = p0, i1 = p0, i2 = p0, i3 = p0;
#pragma unroll 7
    for (int i = 0; i < PCH; ++i) {
        float4 v = *reinterpret_cast<const float4*>(xp + (size_t)(p0 + i) * Cn);
        if (v.x > b0) { b0 = v.x; i0 = p0 + i; }
        if (v.y > b1) { b1 = v.y; i1 = p0 + i; }
        if (v.z > b2) { b2 = v.z; i2 = p0 + i; }
        if (v.w > b3) { b3 = v.w; i3 = p0 + i; }
    }
    uint4* o = reinterpret_cast<uint4*>(part + ((size_t)s * Bn + b) * Cn + c0);
    o[0] = make_uint4(__float_as_uint(b0), (unsigned)i0,
                      __float_as_uint(b1), (unsigned)i1);
    o[1] = make_uint4(__float_as_uint(b2), (unsigned)i2,
                      __float_as_uint(b3), (unsigned)i3);
}

// ---------------------------------------------------------------------------
// Kernel 2: inline partial-fold + ALL output writes.
// A/B change vs R10: x re-read uses REGULAR cacheable loads (R10 used NT
// loads, which bypass the LLC and forced the 205 MB re-read to HBM).
// All output stores stay NT (streaming, no-allocate -> don't evict x).
// ---------------------------------------------------------------------------
__global__ void mask_outputs(const float* __restrict__ x,
                             const float* __restrict__ tp,
                             const uint2* __restrict__ part,
                             float* __restrict__ o0,
                             float* __restrict__ o1,
                             float* __restrict__ o2) {
    __shared__ int sidx[Cn];

    int pc = blockIdx.x % 14;
    int b  = blockIdx.x / 14;
    int t  = threadIdx.x;

    if (t < 128) {
        int c0 = t * 4;
        const uint2* pp = part + (size_t)b * Cn + c0;
        float v0 = -INFINITY, v1 = -INFINITY, v2 = -INFINITY, v3 = -INFINITY;
        int j0 = 0, j1 = 0, j2 = 0, j3 = 0;
#pragma unroll
        for (int s = 0; s < SCH; ++s) {
            const uint2* q = pp + (size_t)s * (Bn * Cn);
            uint4 a = *reinterpret_cast<const uint4*>(q);      // (v0,i0,v1,i1)
            uint4 c = *reinterpret_cast<const uint4*>(q + 2);  // (v2,i2,v3,i3)
            float f0 = __uint_as_float(a.x), f1 = __uint_as_float(a.z);
            float f2 = __uint_as_float(c.x), f3 = __uint_as_float(c.z);
            if (f0 > v0) { v0 = f0; j0 = (int)a.y; }
            if (f1 > v1) { v1 = f1; j1 = (int)a.w; }
            if (f2 > v2) { v2 = f2; j2 = (int)c.y; }
            if (f3 > v3) { v3 = f3; j3 = (int)c.w; }
        }
        sidx[c0 + 0] = j0;
        sidx[c0 + 1] = j1;
        sidx[c0 + 2] = j2;
        sidx[c0 + 3] = j3;
    }
    __syncthreads();

    int ci = t & 127;
    int c0 = ci * 4;
    int ph = t >> 7;
    int p0 = pc * PPB + ph * PPT;

    int4 iv = *reinterpret_cast<const int4*>(sidx + c0);
    const float* t0p = tp + (size_t)iv.x * Pn;
    const float* t1p = tp + (size_t)iv.y * Pn;
    const float* t2p = tp + (size_t)iv.z * Pn;
    const float* t3p = tp + (size_t)iv.w * Pn;

    size_t xbase = (size_t)b * Pn * Cn + c0;

#pragma unroll
    for (int j = 0; j < PPT; j += 4) {
        int p = p0 + j;
        // 4 template rows, 4 consecutive p each (per-lane sequential, L2-hot)
        float4 ta = *reinterpret_cast<const float4*>(t0p + p);
        float4 tb = *reinterpret_cast<const float4*>(t1p + p);
        float4 tc = *reinterpret_cast<const float4*>(t2p + p);
        float4 td = *reinterpret_cast<const float4*>(t3p + p);
        // x re-read: REGULAR loads -> LLC hit (allocated by kernel 1).
        float4 x0 = *reinterpret_cast<const float4*>(x + xbase + (size_t)(p + 0) * Cn);
        float4 x1 = *reinterpret_cast<const float4*>(x + xbase + (size_t)(p + 1) * Cn);
        float4 x2 = *reinterpret_cast<const float4*>(x + xbase + (size_t)(p + 2) * Cn);
        float4 x3 = *reinterpret_cast<const float4*>(x + xbase + (size_t)(p + 3) * Cn);

        size_t q0 = xbase + (size_t)(p + 0) * Cn;
        size_t q1 = xbase + (size_t)(p + 1) * Cn;
        size_t q2 = xbase + (size_t)(p + 2) * Cn;
        size_t q3 = xbase + (size_t)(p + 3) * Cn;

        // o1 = x copy (NT: streaming, no-allocate)
        nt_store4(o1 + q0, x0.x, x0.y, x0.z, x0.w);
        nt_store4(o1 + q1, x1.x, x1.y, x1.z, x1.w);
        nt_store4(o1 + q2, x2.x, x2.y, x2.z, x2.w);
        nt_store4(o1 + q3, x3.x, x3.y, x3.z, x3.w);
        // o0 = relu(x * t)
        nt_store4(o0 + q0, fmaxf(x0.x * ta.x, 0.f), fmaxf(x0.y * tb.x, 0.f),
                           fmaxf(x0.z * tc.x, 0.f), fmaxf(x0.w * td.x, 0.f));
        nt_store4(o0 + q1, fmaxf(x1.x * ta.y, 0.f), fmaxf(x1.y * tb.y, 0.f),
                           fmaxf(x1.z * tc.y, 0.f), fmaxf(x1.w * td.y, 0.f));
        nt_store4(o0 + q2, fmaxf(x2.x * ta.z, 0.f), fmaxf(x2.y * tb.z, 0.f),
                           fmaxf(x2.z * tc.z, 0.f), fmaxf(x2.w * td.z, 0.f));
        nt_store4(o0 + q3, fmaxf(x3.x * ta.w, 0.f), fmaxf(x3.y * tb.w, 0.f),
                           fmaxf(x3.z * tc.w, 0.f), fmaxf(x3.w * td.w, 0.f));
        // o2 = templates
        nt_store4(o2 + q0, ta.x, tb.x, tc.x, td.x);
        nt_store4(o2 + q1, ta.y, tb.y, tc.y, td.y);
        nt_store4(o2 + q2, ta.z, tb.z, tc.z, td.z);
        nt_store4(o2 + q3, ta.w, tb.w, tc.w, td.w);
    }
}

extern "C" void kernel_launch(void* const* d_in, const int* in_sizes, int n_in,
                              void* d_out, int out_size, void* d_ws, size_t ws_size,
                              hipStream_t stream) {
    const float* x  = (const float*)d_in[0];   // [B,H,W,C] fp32
    const float* tp = (const float*)d_in[1];   // [H,W,H,W] fp32

    const size_t N = (size_t)Bn * Pn * Cn;
    float* o0 = (float*)d_out;                 // masked
    float* o1 = o0 + N;                        // x copy
    float* o2 = o0 + 2 * N;                    // templates

    uint2* part = (uint2*)d_ws;                // [SCH][Bn][Cn] uint2 = 4.19 MB

    argmax_partial<<<Bn * SCH, 128, 0, stream>>>(x, part);
    mask_outputs<<<Bn * 14, 256, 0, stream>>>(x, tp, part, o0, o1, o2);
}